// Round 7
// baseline (106.287 us; speedup 1.0000x reference)
//
#include <hip/hip_runtime.h>
#include <hip/hip_bf16.h>

#define B_    8
#define N_    9225
#define M_    4096
#define K_    32
#define HID_  64
#define DOUT_ 16

typedef __attribute__((ext_vector_type(8))) short short8;
typedef __attribute__((ext_vector_type(4))) float floatx4;
typedef __attribute__((ext_vector_type(2))) float f32x2;

static __device__ __forceinline__ short f2bf(float f) {
    __hip_bfloat16 h = __float2bfloat16(f);
    return __builtin_bit_cast(short, h);
}
static __device__ __forceinline__ float bf2f(short s) {
    unsigned u = ((unsigned)(unsigned short)s) << 16;
    return __builtin_bit_cast(float, u);
}
static __device__ __forceinline__ f32x2 splat2(float v) { return (f32x2){v, v}; }

// Sum over each 16-lane DPP row via row_shr tree; lane (row*16+15) holds the sum.
static __device__ __forceinline__ float row16_sum(float v) {
    int t;
    t = __builtin_amdgcn_update_dpp(0, __builtin_bit_cast(int, v), 0x111, 0xF, 0xF, true);
    v += __builtin_bit_cast(float, t);
    t = __builtin_amdgcn_update_dpp(0, __builtin_bit_cast(int, v), 0x112, 0xF, 0xF, true);
    v += __builtin_bit_cast(float, t);
    t = __builtin_amdgcn_update_dpp(0, __builtin_bit_cast(int, v), 0x114, 0xF, 0xF, true);
    v += __builtin_bit_cast(float, t);
    t = __builtin_amdgcn_update_dpp(0, __builtin_bit_cast(int, v), 0x118, 0xF, 0xF, true);
    v += __builtin_bit_cast(float, t);
    return v;
}

// Packed-Pade gelu (R13-validated, absmax 0.0625): tanh via Pade(5,4),
// f32x2 throughout, 1 transcendental (rcp) per element.
static __device__ __forceinline__ f32x2 gelu2(f32x2 x) {
    const f32x2 xsq = x * x;
    const f32x2 t   = __builtin_elementwise_fma(xsq, splat2(0.035677408f), splat2(0.79788456f));
    const f32x2 z   = x * t;
    const f32x2 u   = z * z;
    const f32x2 a   = u + splat2(105.0f);
    const f32x2 nin = __builtin_elementwise_fma(u, a, splat2(945.0f));
    const f32x2 num = z * nin;
    const f32x2 bq  = __builtin_elementwise_fma(u, splat2(15.0f), splat2(420.0f));
    const f32x2 den = __builtin_elementwise_fma(u, bq, splat2(945.0f));
    const f32x2 r   = { __builtin_amdgcn_rcpf(den[0]), __builtin_amdgcn_rcpf(den[1]) };
    f32x2 th = num * r;
    th = __builtin_elementwise_min(__builtin_elementwise_max(th, splat2(-1.0f)), splat2(1.0f));
    const f32x2 hx = x * splat2(0.5f);
    return __builtin_elementwise_fma(hx, th, hx);
}

// R18: load-all-then-compute. R17's counters localized the R2-R17 pin:
// phase throughput is fixed at ~6/us/CU (65,536 phases; invariant to VALU
// mix, addresses 80-144, waves 10-16/CU), each wave stalls ~3100 of ~3900
// cycles per phase on gather latency, and VGPR_Count=64 proves the compiler
// SANK the declared 4-deep prefetch to use sites (declared state alone is
// ~140 VGPR) -- every phase ate full scattered-L2/L3 latency serially.
// Fix: issue ALL 24 gathers (8 phases x {f_y, w, y}) in one burst, then
// sched_barrier(0) so the scheduler cannot sink loads into compute, then 8
// back-to-back phases. In-order vmcnt -> progressive drain (phase p waits
// vmcnt(3*(7-p)) overlapped with earlier compute). One stall per 8 phases.
// launch_bounds(256,2) lifts the VGPR cap so the burst state can live;
// occupancy follows actual VGPR (~150 -> 3 waves/SIMD), per-wave duty rises
// 20%->~85% -> VALU saturates. Math chain identical to R13-R17 (absmax
// 0.0625): hi/lo k-packed layer-1, re-indexed W2 frag, packed-Pade gelu,
// zero LDS/barriers, XCD pin.
__global__ __launch_bounds__(256, 2) void it_kernel(
    const float* __restrict__ y,
    const float* __restrict__ x,
    const float* __restrict__ f_y,
    const float* __restrict__ weights,
    const float* __restrict__ W1,   // [4][64] row-major
    const float* __restrict__ b1,   // [64]
    const float* __restrict__ W2,   // [64][16] row-major
    const float* __restrict__ b2,   // [16]
    const int*   __restrict__ nbr,  // [B][M][K] int32
    float*       __restrict__ out)  // [B][M][16]
{
    const int tid  = threadIdx.x;
    const int lane = tid & 63;
    const int q    = lane >> 4;    // quad 0..3
    const int nlo  = lane & 15;
    const bool q0  = (q == 0);

    const int blk   = blockIdx.x;
    const int batch = blk & 7;          // XCD pin (round-robin heuristic)
    const int pblk  = blk >> 3;         // 0..255 within batch
    const int wid   = tid >> 6;         // wave 0..3
    const int row0  = __builtin_amdgcn_readfirstlane(batch * M_ + pblk * 16 + wid * 4);
    const int bbase = batch * N_;

    // ---- neighbor indices for all 8 phases: issue FIRST (everything hangs
    //      off them; coalesced 64B lines) ----
    int raw[8];
    #pragma unroll
    for (int ph = 0; ph < 8; ++ph) {
        const int it = ph >> 1, h = ph & 1;
        raw[ph] = nbr[(size_t)(row0 + it) * K_ + h * 16 + nlo];
    }

    // ---- W1^T A-fragments, hi/lo k-packed (R14-validated) ----
    short8 w1h[4];
    #pragma unroll
    for (int t = 0; t < 4; ++t) {
        #pragma unroll
        for (int jj = 0; jj < 4; ++jj) {
            const float wv = W1[jj * HID_ + t * 16 + nlo];
            const short b  = q0 ? f2bf(wv) : (short)0;
            w1h[t][jj]     = b;
            w1h[t][jj + 4] = b;
        }
    }

    // ---- W2 A-fragment with layer-1-layout re-index (R13-validated) ----
    short8 w2f[2];
    #pragma unroll
    for (int ch = 0; ch < 2; ++ch)
        #pragma unroll
        for (int jj = 0; jj < 8; ++jj) {
            const int H = (ch * 2 + (jj >> 2)) * 16 + q * 4 + (jj & 3);
            w2f[ch][jj] = f2bf(W2[H * DOUT_ + nlo]);
        }

    // ---- biases in VGPRs (zero LDS, zero barriers) ----
    floatx4 b1r[4];
    #pragma unroll
    for (int t = 0; t < 4; ++t)
        b1r[t] = *(const floatx4*)(b1 + t * 16 + q * 4);
    const floatx4 b2r = *(const floatx4*)(b2 + q * 4);

    // ---- per-row x hi/lo bf16 (4 rows) ----
    short xh[8], xl[8];
    #pragma unroll
    for (int it = 0; it < 4; ++it) {
        const float2 xv = *(const float2*)(x + (size_t)(row0 + it) * 2);
        const short h0 = f2bf(xv.x); const short l0 = f2bf(xv.x - bf2f(h0));
        const short h1 = f2bf(xv.y); const short l1 = f2bf(xv.y - bf2f(h1));
        xh[it * 2] = h0; xh[it * 2 + 1] = h1;
        xl[it * 2] = l0; xl[it * 2 + 1] = l1;
    }

    // ---- BURST: all 8 phases' gathers issued back-to-back.
    //      yv2 zero-initialized (q!=0 lanes feed A==0 slots; must not be
    //      stale-NaN since MFMA propagates 0*NaN). Invalid neighbors load
    //      index 0 and are killed by sw=0 at the accumulate. ----
    float2 yv2[8]; float sw[8]; floatx4 fv[8];
    #pragma unroll
    for (int i = 0; i < 8; ++i) yv2[i] = (float2){0.0f, 0.0f};
    #pragma unroll
    for (int P = 0; P < 8; ++P) {
        const int rv  = raw[P];
        const int vld = rv >= 0;
        const int bn  = bbase + (vld ? rv : 0);
        fv[P] = *(const floatx4*)(f_y + (size_t)bn * 16 + q * 4);
        const float wv_ = weights[bn];
        sw[P] = vld ? wv_ : 0.0f;
        if (q0) yv2[P] = *(const float2*)(y + (size_t)bn * 2);
    }
    // Scheduler fence: loads above may not be sunk into the compute below.
    __builtin_amdgcn_sched_barrier(0);

    float partial[4] = {0.f, 0.f, 0.f, 0.f};
    #pragma unroll
    for (int ph = 0; ph < 8; ++ph) {
        const int it = ph >> 1;

        // ---- input B-fragment, hi at k=0..3, lo at k=4..7 (A zero elsewhere) ----
        const float y0 = yv2[ph].x, y1 = yv2[ph].y;
        const short yh0 = f2bf(y0); const short yl0 = f2bf(y0 - bf2f(yh0));
        const short yh1 = f2bf(y1); const short yl1 = f2bf(y1 - bf2f(yh1));
        const short8 bfull = { yh0, yh1, xh[it * 2], xh[it * 2 + 1],
                               yl0, yl1, xl[it * 2], xl[it * 2 + 1] };

        // ---- layer 1: one MFMA per 16-hid tile (hi+lo k-packed) ----
        floatx4 a1[4];
        #pragma unroll
        for (int t = 0; t < 4; ++t) {
            a1[t] = b1r[t];
            a1[t] = __builtin_amdgcn_mfma_f32_16x16x32_bf16(w1h[t], bfull, a1[t], 0, 0, 0);
        }

        // ---- gelu (packed) + pack to bf16 B-frag slots ----
        short hv[16];
        #pragma unroll
        for (int t = 0; t < 4; ++t) {
            const f32x2 g01 = gelu2((f32x2){a1[t][0], a1[t][1]});
            const f32x2 g23 = gelu2((f32x2){a1[t][2], a1[t][3]});
            hv[t * 4 + 0] = f2bf(g01[0]); hv[t * 4 + 1] = f2bf(g01[1]);
            hv[t * 4 + 2] = f2bf(g23[0]); hv[t * 4 + 3] = f2bf(g23[1]);
        }
        const short8 hf0 = {hv[0], hv[1], hv[2],  hv[3],  hv[4],  hv[5],  hv[6],  hv[7]};
        const short8 hf1 = {hv[8], hv[9], hv[10], hv[11], hv[12], hv[13], hv[14], hv[15]};

        // ---- layer 2: kval[c][elem] = W2^T . h + b2 ----
        floatx4 acc = b2r;
        acc = __builtin_amdgcn_mfma_f32_16x16x32_bf16(w2f[0], hf0, acc, 0, 0, 0);
        acc = __builtin_amdgcn_mfma_f32_16x16x32_bf16(w2f[1], hf1, acc, 0, 0, 0);

        const floatx4 fvp = fv[ph];
        const float   s   = sw[ph];          // 0 for invalid neighbors
        #pragma unroll
        for (int r = 0; r < 4; ++r)
            partial[r] = fmaf(acc[r], fvp[r] * s, partial[r]);

        if (ph & 1) {   // finished a row: reduce over 16 elem-lanes, store
            #pragma unroll
            for (int r = 0; r < 4; ++r) partial[r] = row16_sum(partial[r]);
            if (nlo == 15) {
                floatx4 o = {partial[0], partial[1], partial[2], partial[3]};
                *(floatx4*)(out + (size_t)(row0 + it) * DOUT_ + q * 4) = o;
            }
            #pragma unroll
            for (int r = 0; r < 4; ++r) partial[r] = 0.f;
        }
    }
}

extern "C" void kernel_launch(void* const* d_in, const int* in_sizes, int n_in,
                              void* d_out, int out_size, void* d_ws, size_t ws_size,
                              hipStream_t stream) {
    const float* y   = (const float*)d_in[0];
    const float* x   = (const float*)d_in[1];
    const float* f_y = (const float*)d_in[2];
    const float* w   = (const float*)d_in[3];
    const float* W1  = (const float*)d_in[4];
    const float* b1  = (const float*)d_in[5];
    const float* W2  = (const float*)d_in[6];
    const float* b2  = (const float*)d_in[7];
    const int*   nbr = (const int*)d_in[8];
    float* out = (float*)d_out;

    // Single dispatch. 2048 blocks: 256 per batch (16 rows/block),
    // batch = blk & 7 -> XCD pin.
    dim3 grid(B_ * M_ / 16), block(256);
    hipLaunchKernelGGL(it_kernel, grid, block, 0, stream,
                       y, x, f_y, w, W1, b1, W2, b2, nbr, out);
}